// Round 1
// baseline (541.023 us; speedup 1.0000x reference)
//
#include <hip/hip_runtime.h>

#define EPSV 1e-5f
#define HW 3136   // 56*56

// ---------------------------------------------------------------------------
// Grouped 3x3 conv (G1=64 groups, G2=4 parallel convs) + bias + BN + ReLU.
// Output channel c = i*64 + k reads input channels k*4..k*4+3, weights w[i,k].
// Block: 256 threads, handles one (b, k, half: 28 rows).
// ---------------------------------------------------------------------------
__global__ __launch_bounds__(256) void gconv_bn_relu(
    const float* __restrict__ in,    // [32,256,56,56]
    const float* __restrict__ w,     // [4,64,4,3,3]
    const float* __restrict__ bias,  // [256], index i*64+k
    const float* __restrict__ bng, const float* __restrict__ bnb,
    const float* __restrict__ bnm, const float* __restrict__ bnv,
    float* __restrict__ out)         // [32,256,56,56]
{
    const int tid  = threadIdx.x;
    const int blk  = blockIdx.x;
    const int tile = blk & 1;         // rows 0-27 or 28-55
    const int k    = (blk >> 1) & 63;
    const int b    = blk >> 7;
    const int y0   = tile * 28;

    __shared__ float sIn[4][30][58];  // 4 in-ch, rows y0-1..y0+28, cols -1..56

    const float* inb = in + ((size_t)(b * 256 + k * 4)) * HW;
    for (int idx = tid; idx < 4 * 30 * 58; idx += 256) {
        int cc  = idx / (30 * 58);
        int rem = idx - cc * (30 * 58);
        int r   = rem / 58;
        int col = rem - r * 58;
        int gy  = y0 - 1 + r;
        int gx  = col - 1;
        float v = 0.f;
        if ((unsigned)gy < 56u && (unsigned)gx < 56u)
            v = inb[cc * HW + gy * 56 + gx];
        sIn[cc][r][col] = v;
    }
    __syncthreads();

    if (tid >= 224) return;           // 28 rows * 8 x-strips
    const int row = tid >> 3;         // 0..27
    const int x0  = (tid & 7) * 7;    // 0,7,..,49

    float acc[4][7];
#pragma unroll
    for (int i = 0; i < 4; ++i)
#pragma unroll
        for (int p = 0; p < 7; ++p) acc[i][p] = 0.f;

    const int wbase = k * 36;         // + i*64*36... see index below
#pragma unroll
    for (int cc = 0; cc < 4; ++cc) {
#pragma unroll
        for (int dy = 0; dy < 3; ++dy) {
            float v[9];
#pragma unroll
            for (int j = 0; j < 9; ++j) v[j] = sIn[cc][row + dy][x0 + j];
#pragma unroll
            for (int i = 0; i < 4; ++i) {
                // block-uniform weight index -> scalar loads
                const float* wp = w + (size_t)(i * 64) * 36 + wbase + cc * 9 + dy * 3;
                const float w0 = wp[0], w1 = wp[1], w2 = wp[2];
#pragma unroll
                for (int p = 0; p < 7; ++p)
                    acc[i][p] += w0 * v[p] + w1 * v[p + 1] + w2 * v[p + 2];
            }
        }
    }

    const int y = y0 + row;
#pragma unroll
    for (int i = 0; i < 4; ++i) {
        const int c = i * 64 + k;     // uniform
        const float sc = bng[c] * rsqrtf(bnv[c] + EPSV);
        const float sh = bias[c] * sc + (bnb[c] - bnm[c] * sc);
        float* op = out + (((size_t)(b * 256 + c)) * 56 + y) * 56 + x0;
#pragma unroll
        for (int p = 0; p < 7; ++p) {
            float vv = acc[i][p] * sc + sh;
            op[p] = vv > 0.f ? vv : 0.f;
        }
    }
}

// ---------------------------------------------------------------------------
// Grouped 1x1 conv (4 groups of 64->64) + bias + BN + ReLU.
// Block: 256 threads = 8 o-groups x 32 px-groups; thread tile 8 outch x 4 px.
// Block handles (b, g, 128-px tile). Acts in LDS, weights via L1/L2 float4.
// ---------------------------------------------------------------------------
__global__ __launch_bounds__(256) void pw_bn_relu(
    const float* __restrict__ in,    // [32,256,56,56]
    const float* __restrict__ pw,    // [256,64]
    const float* __restrict__ pb,    // [256]
    const float* __restrict__ bng, const float* __restrict__ bnb,
    const float* __restrict__ bnm, const float* __restrict__ bnv,
    float* __restrict__ out)
{
    const int tid = threadIdx.x;
    const int blk = blockIdx.x;
    const int b   = blk / 100;
    const int rem = blk - b * 100;
    const int g   = rem / 25;
    const int t   = rem - g * 25;
    const int p0  = t * 128;          // last tile: 3072..3135 (64 px)

    __shared__ float sAct[64][128];

    const float* inb = in + ((size_t)(b * 256 + g * 64)) * HW;
    for (int idx = tid; idx < 64 * 32; idx += 256) {
        int c  = idx >> 5;
        int j4 = idx & 31;
        int p  = p0 + j4 * 4;
        float4 v = make_float4(0.f, 0.f, 0.f, 0.f);
        if (p < HW) v = *(const float4*)(inb + c * HW + p);
        *(float4*)(&sAct[c][j4 * 4]) = v;
    }
    __syncthreads();

    const int og = tid >> 5;          // 0..7  -> 8 out channels
    const int px = (tid & 31) * 4;    // 0..124

    float acc[8][4];
#pragma unroll
    for (int i = 0; i < 8; ++i)
#pragma unroll
        for (int p = 0; p < 4; ++p) acc[i][p] = 0.f;

    const float* wb = pw + ((size_t)(g * 64 + og * 8)) * 64;
    for (int c = 0; c < 64; c += 4) {
        float4 A0 = *(const float4*)(&sAct[c + 0][px]);
        float4 A1 = *(const float4*)(&sAct[c + 1][px]);
        float4 A2 = *(const float4*)(&sAct[c + 2][px]);
        float4 A3 = *(const float4*)(&sAct[c + 3][px]);
#pragma unroll
        for (int i = 0; i < 8; ++i) {
            float4 wv = *(const float4*)(wb + i * 64 + c);  // w[o][c..c+3]
            acc[i][0] += wv.x * A0.x + wv.y * A1.x + wv.z * A2.x + wv.w * A3.x;
            acc[i][1] += wv.x * A0.y + wv.y * A1.y + wv.z * A2.y + wv.w * A3.y;
            acc[i][2] += wv.x * A0.z + wv.y * A1.z + wv.z * A2.z + wv.w * A3.z;
            acc[i][3] += wv.x * A0.w + wv.y * A1.w + wv.z * A2.w + wv.w * A3.w;
        }
    }

    const int p = p0 + px;
    if (p < HW) {                     // p%4==0 and HW%4==0 -> full float4 or none
#pragma unroll
        for (int i = 0; i < 8; ++i) {
            const int o = g * 64 + og * 8 + i;
            const float sc = bng[o] * rsqrtf(bnv[o] + EPSV);
            const float sh = pb[o] * sc + (bnb[o] - bnm[o] * sc);
            float4 r;
            r.x = fmaxf(acc[i][0] * sc + sh, 0.f);
            r.y = fmaxf(acc[i][1] * sc + sh, 0.f);
            r.z = fmaxf(acc[i][2] * sc + sh, 0.f);
            r.w = fmaxf(acc[i][3] * sc + sh, 0.f);
            *(float4*)(out + ((size_t)(b * 256 + o)) * HW + p) = r;
        }
    }
}

extern "C" void kernel_launch(void* const* d_in, const int* in_sizes, int n_in,
                              void* d_out, int out_size, void* d_ws, size_t ws_size,
                              hipStream_t stream) {
    const float* x     = (const float*)d_in[0];
    const float* w1    = (const float*)d_in[1];
    const float* b1    = (const float*)d_in[2];
    const float* bn1ag = (const float*)d_in[3];
    const float* bn1ab = (const float*)d_in[4];
    const float* bn1am = (const float*)d_in[5];
    const float* bn1av = (const float*)d_in[6];
    const float* pw1   = (const float*)d_in[7];
    const float* pb1   = (const float*)d_in[8];
    const float* bn1bg = (const float*)d_in[9];
    const float* bn1bb = (const float*)d_in[10];
    const float* bn1bm = (const float*)d_in[11];
    const float* bn1bv = (const float*)d_in[12];
    const float* w2    = (const float*)d_in[13];
    const float* b2    = (const float*)d_in[14];
    const float* bn2ag = (const float*)d_in[15];
    const float* bn2ab = (const float*)d_in[16];
    const float* bn2am = (const float*)d_in[17];
    const float* bn2av = (const float*)d_in[18];
    const float* pw2   = (const float*)d_in[19];
    const float* pb2   = (const float*)d_in[20];
    const float* bn2bg = (const float*)d_in[21];
    const float* bn2bb = (const float*)d_in[22];
    const float* bn2bm = (const float*)d_in[23];
    const float* bn2bv = (const float*)d_in[24];

    float* buf  = (float*)d_ws;   // needs 32*256*56*56*4 = 102,760,448 B
    float* outp = (float*)d_out;

    // stage 1: gconv1 + bn1a + relu   -> buf
    gconv_bn_relu<<<32 * 64 * 2, 256, 0, stream>>>(x, w1, b1, bn1ag, bn1ab, bn1am, bn1av, buf);
    // stage 2: pw1 + bn1b + relu     -> d_out (used as scratch)
    pw_bn_relu<<<32 * 4 * 25, 256, 0, stream>>>(buf, pw1, pb1, bn1bg, bn1bb, bn1bm, bn1bv, outp);
    // stage 3: gconv2 + bn2a + relu  -> buf
    gconv_bn_relu<<<32 * 64 * 2, 256, 0, stream>>>(outp, w2, b2, bn2ag, bn2ab, bn2am, bn2av, buf);
    // stage 4: pw2 + bn2b + relu     -> d_out
    pw_bn_relu<<<32 * 4 * 25, 256, 0, stream>>>(buf, pw2, pb2, bn2bg, bn2bb, bn2bm, bn2bv, outp);
}

// Round 2
// 477.126 us; speedup vs baseline: 1.1339x; 1.1339x over previous
//
#include <hip/hip_runtime.h>

#define HW 3136      // 56*56
#define SHS 232      // sH row stride: 224 px + 8 pad (232%32==8 -> writes 4-way worst, reads conflict-free)

// One fused residual-stage: grouped3x3 conv + bias + BN + ReLU -> (LDS) -> grouped1x1 conv
// + bias + BN + ReLU -> global.
// Block = (b, g, 4-row tile). g doubles as: pw group index AND gconv conv-index i
// (pw group g reads h channels g*64+k, which are exactly conv i=g outputs, k=0..63).
__global__ __launch_bounds__(256, 2) void fused_stage(
    const float* __restrict__ in,    // [32,256,56,56]
    const float* __restrict__ gw,    // [4,64,4,3,3]  (i,k,cc,dy,dx)
    const float* __restrict__ gb,    // [256] flat (i*64+k)
    const float* __restrict__ bnag, const float* __restrict__ bnab,
    const float* __restrict__ bnam, const float* __restrict__ bnav,
    const float* __restrict__ pw,    // [256,64]
    const float* __restrict__ pb,    // [256]
    const float* __restrict__ bnbg, const float* __restrict__ bnbb,
    const float* __restrict__ bnbm, const float* __restrict__ bnbv,
    float* __restrict__ out)         // [32,256,56,56]
{
    __shared__ float sH[64 * SHS];   // 59392 B: intermediate h[k][r*56+x]
    __shared__ float sW[64 * 64];    // 16384 B: pw weights transposed [c][o]

    const int tid = threadIdx.x;
    const int blk = blockIdx.x;
    const int t   = blk % 14;        // 4-row tile 0..13
    const int g   = (blk / 14) & 3;
    const int b   = blk / 56;
    const int y0  = t * 4;

    // ---- phase 0: stage pw weights for group g, transposed to [c][o] ----
    {
        const int o  = tid & 63;
        const int c0 = (tid >> 6) * 16;
        const float* src = pw + (size_t)(g * 64 + o) * 64 + c0;
        float4 v0 = *(const float4*)(src + 0);
        float4 v1 = *(const float4*)(src + 4);
        float4 v2 = *(const float4*)(src + 8);
        float4 v3 = *(const float4*)(src + 12);
        float tmp[16] = {v0.x, v0.y, v0.z, v0.w, v1.x, v1.y, v1.z, v1.w,
                         v2.x, v2.y, v2.z, v2.w, v3.x, v3.y, v3.z, v3.w};
#pragma unroll
        for (int j = 0; j < 16; ++j)
            sW[(c0 + j) * 64 + o] = tmp[j];   // banks = o%32: 2-way (free)
    }

    // ---- phase 1: grouped 3x3 conv for conv-index g, all 64 groups k ----
    const int k  = tid >> 2;         // 0..63 group (intermediate channel g*64+k)
    const int xs = tid & 3;          // x-strip of 14
    const int x0 = xs * 14;

    float wr[36];                    // gw[g][k][cc][dy][dx], contiguous, 16B-aligned
    {
        const float4* w4 = (const float4*)(gw + (size_t)(g * 64 + k) * 36);
#pragma unroll
        for (int j = 0; j < 9; ++j) {
            float4 v = w4[j];
            wr[4*j+0] = v.x; wr[4*j+1] = v.y; wr[4*j+2] = v.z; wr[4*j+3] = v.w;
        }
    }

    float acc[4][14];
#pragma unroll
    for (int r = 0; r < 4; ++r)
#pragma unroll
        for (int xx = 0; xx < 14; ++xx) acc[r][xx] = 0.f;

#pragma unroll
    for (int cc = 0; cc < 4; ++cc) {
        const float* chp = in + ((size_t)(b * 256 + k * 4 + cc)) * HW;
#pragma unroll
        for (int ry = 0; ry < 6; ++ry) {
            const int gy = y0 - 1 + ry;          // block-uniform after unroll
            if ((unsigned)gy >= 56u) continue;   // zero-pad rows
            const float* rp = chp + gy * 56;
            float rr[16];                        // cols x0-1 .. x0+14
            rr[0]  = (x0 > 0)       ? rp[x0 - 1]  : 0.f;
            rr[15] = (x0 + 14 < 56) ? rp[x0 + 14] : 0.f;
#pragma unroll
            for (int j = 0; j < 7; ++j) {
                float2 v = *(const float2*)(rp + x0 + 2 * j);  // 8B-aligned
                rr[1 + 2*j] = v.x; rr[2 + 2*j] = v.y;
            }
            const int rlo = (ry >= 2) ? ry - 2 : 0;
            const int rhi = (ry <= 3) ? ry : 3;
#pragma unroll
            for (int r = 0; r < 4; ++r) {
                if (r < rlo || r > rhi) continue;  // dead-code after unroll
                const int dy = ry - r;
                const float w0 = wr[cc*9 + dy*3 + 0];
                const float w1 = wr[cc*9 + dy*3 + 1];
                const float w2 = wr[cc*9 + dy*3 + 2];
#pragma unroll
                for (int xx = 0; xx < 14; ++xx)
                    acc[r][xx] = fmaf(w2, rr[xx+2],
                                 fmaf(w1, rr[xx+1],
                                 fmaf(w0, rr[xx], acc[r][xx])));
            }
        }
    }

    // bias + BN-a + ReLU -> sH
    {
        const int c = g * 64 + k;
        const float sc = bnag[c] * rsqrtf(bnav[c] + 1e-5f);
        const float sh = fmaf(gb[c], sc, bnab[c] - bnam[c] * sc);
#pragma unroll
        for (int r = 0; r < 4; ++r)
#pragma unroll
            for (int j = 0; j < 7; ++j) {
                float v0 = fmaxf(fmaf(acc[r][2*j],   sc, sh), 0.f);
                float v1 = fmaxf(fmaf(acc[r][2*j+1], sc, sh), 0.f);
                *(float2*)&sH[k * SHS + r * 56 + x0 + 2*j] = make_float2(v0, v1);
            }
    }
    __syncthreads();

    // ---- phase 2: 64x224 = W[64x64] * sH[64x224] GEMM, 4-out x 14-px tile ----
    const int og = tid >> 4;         // 0..15 -> out channels og*4..og*4+3
    const int pg = tid & 15;         // 0..15 -> px p0..p0+13
    const int p0 = pg * 14;

    float a2[4][14];
#pragma unroll
    for (int i = 0; i < 4; ++i)
#pragma unroll
        for (int xx = 0; xx < 14; ++xx) a2[i][xx] = 0.f;

    for (int c = 0; c < 64; ++c) {
        const float4 wv = *(const float4*)&sW[c * 64 + og * 4];  // broadcast x16
        float hr[14];
#pragma unroll
        for (int j = 0; j < 7; ++j) {
            float2 v = *(const float2*)&sH[c * SHS + p0 + 2*j];  // 16 banks, no conflict
            hr[2*j] = v.x; hr[2*j+1] = v.y;
        }
#pragma unroll
        for (int xx = 0; xx < 14; ++xx) {
            a2[0][xx] = fmaf(wv.x, hr[xx], a2[0][xx]);
            a2[1][xx] = fmaf(wv.y, hr[xx], a2[1][xx]);
            a2[2][xx] = fmaf(wv.z, hr[xx], a2[2][xx]);
            a2[3][xx] = fmaf(wv.w, hr[xx], a2[3][xx]);
        }
    }

    // bias + BN-b + ReLU -> global
#pragma unroll
    for (int i = 0; i < 4; ++i) {
        const int o = g * 64 + og * 4 + i;
        const float sc = bnbg[o] * rsqrtf(bnbv[o] + 1e-5f);
        const float sh = fmaf(pb[o], sc, bnbb[o] - bnbm[o] * sc);
        float* op = out + ((size_t)(b * 256 + o)) * HW + y0 * 56 + p0;
#pragma unroll
        for (int j = 0; j < 7; ++j) {
            float v0 = fmaxf(fmaf(a2[i][2*j],   sc, sh), 0.f);
            float v1 = fmaxf(fmaf(a2[i][2*j+1], sc, sh), 0.f);
            *(float2*)(op + 2*j) = make_float2(v0, v1);
        }
    }
}

extern "C" void kernel_launch(void* const* d_in, const int* in_sizes, int n_in,
                              void* d_out, int out_size, void* d_ws, size_t ws_size,
                              hipStream_t stream) {
    const float* x     = (const float*)d_in[0];
    const float* w1    = (const float*)d_in[1];
    const float* b1    = (const float*)d_in[2];
    const float* bn1ag = (const float*)d_in[3];
    const float* bn1ab = (const float*)d_in[4];
    const float* bn1am = (const float*)d_in[5];
    const float* bn1av = (const float*)d_in[6];
    const float* pw1   = (const float*)d_in[7];
    const float* pb1   = (const float*)d_in[8];
    const float* bn1bg = (const float*)d_in[9];
    const float* bn1bb = (const float*)d_in[10];
    const float* bn1bm = (const float*)d_in[11];
    const float* bn1bv = (const float*)d_in[12];
    const float* w2    = (const float*)d_in[13];
    const float* b2    = (const float*)d_in[14];
    const float* bn2ag = (const float*)d_in[15];
    const float* bn2ab = (const float*)d_in[16];
    const float* bn2am = (const float*)d_in[17];
    const float* bn2av = (const float*)d_in[18];
    const float* pw2   = (const float*)d_in[19];
    const float* pb2   = (const float*)d_in[20];
    const float* bn2bg = (const float*)d_in[21];
    const float* bn2bb = (const float*)d_in[22];
    const float* bn2bm = (const float*)d_in[23];
    const float* bn2bv = (const float*)d_in[24];

    float* mid  = (float*)d_ws;      // 32*256*56*56*4 = 102,760,448 B
    float* outp = (float*)d_out;

    const int grid = 32 * 4 * 14;    // (b, g, tile)

    fused_stage<<<grid, 256, 0, stream>>>(x,   w1, b1, bn1ag, bn1ab, bn1am, bn1av,
                                          pw1, pb1, bn1bg, bn1bb, bn1bm, bn1bv, mid);
    fused_stage<<<grid, 256, 0, stream>>>(mid, w2, b2, bn2ag, bn2ab, bn2am, bn2av,
                                          pw2, pb2, bn2bg, bn2bb, bn2bm, bn2bv, outp);
}